// Round 1
// baseline (275.386 us; speedup 1.0000x reference)
//
#include <hip/hip_runtime.h>
#include <stdint.h>

typedef unsigned short u16;
typedef __bf16 bf16x8 __attribute__((ext_vector_type(8)));
typedef float f32x4 __attribute__((ext_vector_type(4)));
typedef unsigned int u32x4 __attribute__((ext_vector_type(4)));
typedef u16 u16x8 __attribute__((ext_vector_type(8)));

#define MFMA16(a, b, c) __builtin_amdgcn_mfma_f32_16x16x32_bf16((a), (b), (c), 0, 0, 0)

__device__ __forceinline__ u16 f2bf(float f) {
  unsigned u = __float_as_uint(f);
  u += 0x7fff + ((u >> 16) & 1);  // RNE
  return (u16)(u >> 16);
}

__device__ __forceinline__ bf16x8 load_frag(const u16* lds_base, int byteoff) {
  u32x4 v = *(const u32x4*)((const char*)lds_base + byteoff);
  return __builtin_bit_cast(bf16x8, v);
}

#define GLOAD_LDS16(gp, lp)                                                        \
  __builtin_amdgcn_global_load_lds((const __attribute__((address_space(1))) void*)(gp), \
                                   (__attribute__((address_space(3))) void*)(lp), 16, 0, 0)

// Stage ROWS x 64-bf16 tile (128B rows) from global (row stride ld elems) into
// swizzled LDS. Physical 16B-slot `seg` holds logical slot `seg ^ (row&7)`:
// linear LDS dest (global_load_lds requirement) + pre-swizzled global source.
template <int ROWS>
__device__ __forceinline__ void stage_tile(const u16* __restrict__ src, int ld, u16* lds,
                                           int tid) {
  constexpr int SLOTS = ROWS * 8;
#pragma unroll
  for (int it = 0; it < SLOTS / 256; ++it) {
    const int s = it * 256 + tid;
    const int row = s >> 3;
    const int seg = (s & 7) ^ (row & 7);
    const u16* g = src + row * ld + seg * 8;
    u16* l = lds + (it * 256 + (tid & ~63)) * 8;  // wave-uniform base; HW adds lane*16
    GLOAD_LDS16(g, l);
  }
}

// ---------------- converts ----------------

__global__ __launch_bounds__(256) void cvt_x(const float* __restrict__ in,
                                             u16* __restrict__ out) {
  const int i = (int)blockIdx.x * 256 + (int)threadIdx.x;  // 1048576 threads, 8 elems each
  const float4 a = ((const float4*)in)[2 * i];
  const float4 b = ((const float4*)in)[2 * i + 1];
  u16x8 o;
  o[0] = f2bf(a.x); o[1] = f2bf(a.y); o[2] = f2bf(a.z); o[3] = f2bf(a.w);
  o[4] = f2bf(b.x); o[5] = f2bf(b.y); o[6] = f2bf(b.z); o[7] = f2bf(b.w);
  ((u16x8*)out)[i] = o;
}

// W [1024][1024] fp32 row-major -> Wt [1024][1024] bf16, Wt[n][k] = W[k][n]
__global__ __launch_bounds__(256) void cvt_w_t(const float* __restrict__ W,
                                               u16* __restrict__ Wt) {
  __shared__ u16 t[64][65];
  const int tid = (int)threadIdx.x;
  const int r = tid >> 2;             // 0..63
  const int cs = (tid & 3) * 16;      // 0,16,32,48
  const int tr = (int)blockIdx.y * 64;  // k base
  const int tc = (int)blockIdx.x * 64;  // n base
#pragma unroll
  for (int i = 0; i < 16; i += 4) {
    const float4 v = *(const float4*)&W[(size_t)(tr + r) * 1024 + tc + cs + i];
    t[r][cs + i + 0] = f2bf(v.x);
    t[r][cs + i + 1] = f2bf(v.y);
    t[r][cs + i + 2] = f2bf(v.z);
    t[r][cs + i + 3] = f2bf(v.w);
  }
  __syncthreads();
  u16 tmp[16];
#pragma unroll
  for (int i = 0; i < 16; ++i) tmp[i] = t[cs + i][r];
  u16x8 o0, o1;
#pragma unroll
  for (int i = 0; i < 8; ++i) { o0[i] = tmp[i]; o1[i] = tmp[8 + i]; }
  *(u16x8*)&Wt[(size_t)(tc + r) * 1024 + tr + cs] = o0;
  *(u16x8*)&Wt[(size_t)(tc + r) * 1024 + tr + cs + 8] = o1;
}

// ---------------- GEMM: C[8192x1024] = A[8192x1024] @ Bt^T + bias ----------------
// OUT_MODE 0: bf16 row-major; 1: fp32 row-major (final out); 2: bf16 V-transposed [B,H,64,S]

template <int OUT_MODE>
__global__ __launch_bounds__(256) void gemm_bt(const u16* __restrict__ A,
                                               const u16* __restrict__ Bt,
                                               const float* __restrict__ bias,
                                               void* __restrict__ Cout) {
  constexpr int N = 1024, K = 1024;
  __shared__ __align__(16) u16 lds[2 * 128 * 64];  // A tile | Bt tile
  const int tid = (int)threadIdx.x;
  const int w = tid >> 6, lane = tid & 63;
  const int wm = w >> 1, wn = w & 1;
  const int lr = lane & 15, lg = lane >> 4;
  const int mt = (int)blockIdx.y, nt = (int)blockIdx.x;

  const u16* Abase = A + (size_t)mt * 128 * K;
  const u16* Bbase = Bt + (size_t)nt * 128 * K;

  f32x4 acc[4][4] = {};

  for (int k0 = 0; k0 < K; k0 += 64) {
    stage_tile<128>(Abase + k0, K, lds, tid);
    stage_tile<128>(Bbase + k0, K, lds + 128 * 64, tid);
    __syncthreads();
#pragma unroll
    for (int ks = 0; ks < 2; ++ks) {
      bf16x8 af[4], bf[4];
#pragma unroll
      for (int i = 0; i < 4; ++i) {
        const int ar = wm * 64 + i * 16 + lr;
        af[i] = load_frag(lds, ar * 128 + ((ks * 64 + lg * 16) ^ ((ar & 7) << 4)));
        const int br = wn * 64 + i * 16 + lr;
        bf[i] = load_frag(lds + 128 * 64, br * 128 + ((ks * 64 + lg * 16) ^ ((br & 7) << 4)));
      }
#pragma unroll
      for (int mf = 0; mf < 4; ++mf)
#pragma unroll
        for (int nf = 0; nf < 4; ++nf) acc[mf][nf] = MFMA16(af[mf], bf[nf], acc[mf][nf]);
    }
    __syncthreads();
  }

#pragma unroll
  for (int mf = 0; mf < 4; ++mf) {
#pragma unroll
    for (int nf = 0; nf < 4; ++nf) {
      const int col = nt * 128 + wn * 64 + nf * 16 + lr;
      const float bv = bias[col];
#pragma unroll
      for (int r = 0; r < 4; ++r) {
        const int row = mt * 128 + wm * 64 + mf * 16 + lg * 4 + r;
        const float v = acc[mf][nf][r] + bv;
        if (OUT_MODE == 0) {
          ((u16*)Cout)[(size_t)row * N + col] = f2bf(v);
        } else if (OUT_MODE == 1) {
          ((float*)Cout)[(size_t)row * N + col] = v;
        } else {
          const int b = row >> 11, s = row & 2047;
          const int h = col >> 6, d = col & 63;
          ((u16*)Cout)[(size_t)((b * 16 + h) * 64 + d) * 2048 + s] = f2bf(v);
        }
      }
    }
  }
}

// ---------------- flash attention (causal) ----------------
// grid (B*H=64, S/128=16); 4 waves, wave w owns q-rows [w*32, w*32+32)

__global__ __launch_bounds__(256) void attn_fwd(const u16* __restrict__ Qb,
                                                const u16* __restrict__ Kb,
                                                const u16* __restrict__ Vt,
                                                u16* __restrict__ Ab) {
  __shared__ __align__(16) u16 Qs[128 * 64];
  __shared__ __align__(16) u16 Ks[64 * 64];
  __shared__ __align__(16) u16 Vs[64 * 64];
  __shared__ __align__(16) u16 Ps[128 * 64];

  const int tid = (int)threadIdx.x;
  const int w = tid >> 6, lane = tid & 63;
  const int lr = lane & 15, lg = lane >> 4;
  const int bh = (int)blockIdx.x, qt = (int)blockIdx.y;
  const int b = bh >> 4, h = bh & 15;
  const int q0 = qt * 128;

  stage_tile<128>(Qb + (size_t)(b * 2048 + q0) * 1024 + h * 64, 1024, Qs, tid);
  __syncthreads();

  bf16x8 qf[2][2];
#pragma unroll
  for (int mf = 0; mf < 2; ++mf)
#pragma unroll
    for (int ks = 0; ks < 2; ++ks) {
      const int qr = w * 32 + mf * 16 + lr;
      qf[mf][ks] = load_frag(Qs, qr * 128 + ((ks * 64 + lg * 16) ^ ((qr & 7) << 4)));
    }

  float m_run[2][4], l_run[2][4];
  f32x4 acc_o[2][4] = {};
#pragma unroll
  for (int mf = 0; mf < 2; ++mf)
#pragma unroll
    for (int r = 0; r < 4; ++r) { m_run[mf][r] = -3.0e38f; l_run[mf][r] = 0.f; }

  const int ntiles = qt * 2 + 2;
  const int wq_lo = q0 + w * 32;

  for (int j = 0; j < ntiles; ++j) {
    const int s0 = j * 64;
    stage_tile<64>(Kb + (size_t)(b * 2048 + s0) * 1024 + h * 64, 1024, Ks, tid);
    stage_tile<64>(Vt + (size_t)(bh * 64) * 2048 + s0, 2048, Vs, tid);
    __syncthreads();
    if (s0 <= wq_lo + 31) {  // wave-uniform skip of fully-masked tiles
      // QK^T
      f32x4 accs[2][4] = {};
#pragma unroll
      for (int ks = 0; ks < 2; ++ks)
#pragma unroll
        for (int nf = 0; nf < 4; ++nf) {
          const int kr = nf * 16 + lr;
          const bf16x8 kf = load_frag(Ks, kr * 128 + ((ks * 64 + lg * 16) ^ ((kr & 7) << 4)));
#pragma unroll
          for (int mf = 0; mf < 2; ++mf) accs[mf][nf] = MFMA16(qf[mf][ks], kf, accs[mf][nf]);
        }
      // online softmax (row lives in 16 lanes; width-16 xor reduce)
#pragma unroll
      for (int mf = 0; mf < 2; ++mf) {
#pragma unroll
        for (int r = 0; r < 4; ++r) {
          const int qrow = wq_lo + mf * 16 + lg * 4 + r;
          float sv[4];
          float mx = -3.0e38f;
#pragma unroll
          for (int nf = 0; nf < 4; ++nf) {
            float v = accs[mf][nf][r] * 0.125f;
            if (s0 + nf * 16 + lr > qrow) v = -1.0e30f;  // causal mask
            sv[nf] = v;
            mx = fmaxf(mx, v);
          }
          mx = fmaxf(mx, __shfl_xor(mx, 1, 16));
          mx = fmaxf(mx, __shfl_xor(mx, 2, 16));
          mx = fmaxf(mx, __shfl_xor(mx, 4, 16));
          mx = fmaxf(mx, __shfl_xor(mx, 8, 16));
          const float mnew = fmaxf(m_run[mf][r], mx);
          const float alpha = __expf(m_run[mf][r] - mnew);
          m_run[mf][r] = mnew;
          float rs = 0.f;
          const int prow = w * 32 + mf * 16 + lg * 4 + r;
#pragma unroll
          for (int nf = 0; nf < 4; ++nf) {
            const float p = __expf(sv[nf] - mnew);
            rs += p;
            const int pb = ((nf * 16 + lr) * 2) ^ ((prow & 7) << 4);
            *(u16*)((char*)Ps + prow * 128 + pb) = f2bf(p);
          }
          rs += __shfl_xor(rs, 1, 16);
          rs += __shfl_xor(rs, 2, 16);
          rs += __shfl_xor(rs, 4, 16);
          rs += __shfl_xor(rs, 8, 16);
          l_run[mf][r] = l_run[mf][r] * alpha + rs;
#pragma unroll
          for (int df = 0; df < 4; ++df) acc_o[mf][df][r] *= alpha;
        }
      }
      // PV (P read back in A-fragment layout; same-wave LDS ordering is in-order)
#pragma unroll
      for (int ks = 0; ks < 2; ++ks) {
        bf16x8 vf[4];
#pragma unroll
        for (int df = 0; df < 4; ++df) {
          const int vr = df * 16 + lr;
          vf[df] = load_frag(Vs, vr * 128 + ((ks * 64 + lg * 16) ^ ((vr & 7) << 4)));
        }
#pragma unroll
        for (int mf = 0; mf < 2; ++mf) {
          const int pr = w * 32 + mf * 16 + lr;
          const bf16x8 pf = load_frag(Ps, pr * 128 + ((ks * 64 + lg * 16) ^ ((pr & 7) << 4)));
#pragma unroll
          for (int df = 0; df < 4; ++df) acc_o[mf][df] = MFMA16(pf, vf[df], acc_o[mf][df]);
        }
      }
    }
    __syncthreads();
  }

#pragma unroll
  for (int mf = 0; mf < 2; ++mf)
#pragma unroll
    for (int df = 0; df < 4; ++df)
#pragma unroll
      for (int r = 0; r < 4; ++r) {
        const int row = b * 2048 + q0 + w * 32 + mf * 16 + lg * 4 + r;
        const int col = h * 64 + df * 16 + lr;
        Ab[(size_t)row * 1024 + col] = f2bf(acc_o[mf][df][r] / l_run[mf][r]);
      }
}

// ---------------- launch ----------------

extern "C" void kernel_launch(void* const* d_in, const int* in_sizes, int n_in, void* d_out,
                              int out_size, void* d_ws, size_t ws_size, hipStream_t stream) {
  const float* X = (const float*)d_in[0];
  const float* Wq = (const float*)d_in[1];
  const float* bq = (const float*)d_in[2];
  const float* Wk = (const float*)d_in[3];
  const float* bk = (const float*)d_in[4];
  const float* Wv = (const float*)d_in[5];
  const float* bv = (const float*)d_in[6];
  const float* Wo = (const float*)d_in[7];
  const float* bo = (const float*)d_in[8];
  float* out = (float*)d_out;

  // workspace layout (u16 elements), total 92,274,688 bytes
  u16* ws = (u16*)d_ws;
  u16* Xb = ws;                    // 8192x1024 bf16 X
  u16* Wqt = Xb + 8388608;         // 1024x1024 bf16 Wq^T
  u16* Wkt = Wqt + 1048576;
  u16* Wvt = Wkt + 1048576;
  u16* Wot = Wvt + 1048576;
  u16* Qb = Wot + 1048576;         // 8192x1024 bf16 Q
  u16* Kb = Qb + 8388608;          // 8192x1024 bf16 K
  u16* Vt = Kb + 8388608;          // [4][16][64][2048] bf16 V^T
  u16* Ab = Vt + 8388608;          // 8192x1024 bf16 attn out (merged heads)

  cvt_x<<<4096, 256, 0, stream>>>(X, Xb);
  dim3 wtg(16, 16);
  cvt_w_t<<<wtg, 256, 0, stream>>>(Wq, Wqt);
  cvt_w_t<<<wtg, 256, 0, stream>>>(Wk, Wkt);
  cvt_w_t<<<wtg, 256, 0, stream>>>(Wv, Wvt);
  cvt_w_t<<<wtg, 256, 0, stream>>>(Wo, Wot);

  dim3 gg(8, 64);
  gemm_bt<0><<<gg, 256, 0, stream>>>(Xb, Wqt, bq, Qb);
  gemm_bt<0><<<gg, 256, 0, stream>>>(Xb, Wkt, bk, Kb);
  gemm_bt<2><<<gg, 256, 0, stream>>>(Xb, Wvt, bv, Vt);

  dim3 ag(64, 16);
  attn_fwd<<<ag, 256, 0, stream>>>(Qb, Kb, Vt, Ab);

  gemm_bt<1><<<gg, 256, 0, stream>>>(Ab, Wot, bo, out);
}

// Round 3
// 251.855 us; speedup vs baseline: 1.0934x; 1.0934x over previous
//
#include <hip/hip_runtime.h>
#include <stdint.h>

typedef unsigned short u16;
typedef __bf16 bf16x8 __attribute__((ext_vector_type(8)));
typedef float f32x4 __attribute__((ext_vector_type(4)));
typedef float f32x16 __attribute__((ext_vector_type(16)));
typedef unsigned int u32x4 __attribute__((ext_vector_type(4)));
typedef u16 u16x8 __attribute__((ext_vector_type(8)));
typedef u16 u16x4 __attribute__((ext_vector_type(4)));

#define MFMA16(a, b, c) __builtin_amdgcn_mfma_f32_16x16x32_bf16((a), (b), (c), 0, 0, 0)
#define MFMA32(a, b, c) __builtin_amdgcn_mfma_f32_32x32x16_bf16((a), (b), (c), 0, 0, 0)

__device__ __forceinline__ u16 f2bf(float f) {
  unsigned u = __float_as_uint(f);
  u += 0x7fff + ((u >> 16) & 1);  // RNE
  return (u16)(u >> 16);
}

__device__ __forceinline__ unsigned pack_bf2(float lo, float hi) {
  return (unsigned)f2bf(lo) | ((unsigned)f2bf(hi) << 16);
}

__device__ __forceinline__ bf16x8 load_frag(const u16* lds_base, int byteoff) {
  u32x4 v = *(const u32x4*)((const char*)lds_base + byteoff);
  return __builtin_bit_cast(bf16x8, v);
}

#define GLOAD_LDS16(gp, lp)                                                        \
  __builtin_amdgcn_global_load_lds((const __attribute__((address_space(1))) void*)(gp), \
                                   (__attribute__((address_space(3))) void*)(lp), 16, 0, 0)

// Stage ROWS x 64-bf16 tile (128B rows) from global (row stride ld elems) into
// swizzled LDS. Physical 16B-slot `seg` holds logical slot `seg ^ (row&7)`.
template <int ROWS>
__device__ __forceinline__ void stage_tile(const u16* __restrict__ src, int ld, u16* lds,
                                           int tid) {
  constexpr int SLOTS = ROWS * 8;
#pragma unroll
  for (int it = 0; it < SLOTS / 256; ++it) {
    const int s = it * 256 + tid;
    const int row = s >> 3;
    const int seg = (s & 7) ^ (row & 7);
    const u16* g = src + row * ld + seg * 8;
    u16* l = lds + (it * 256 + (tid & ~63)) * 8;  // wave-uniform base; HW adds lane*16
    GLOAD_LDS16(g, l);
  }
}

// ---------------- converts ----------------

__global__ __launch_bounds__(256) void cvt_x(const float* __restrict__ in,
                                             u16* __restrict__ out) {
  const int i = (int)blockIdx.x * 256 + (int)threadIdx.x;
  const float4 a = ((const float4*)in)[2 * i];
  const float4 b = ((const float4*)in)[2 * i + 1];
  u16x8 o;
  o[0] = f2bf(a.x); o[1] = f2bf(a.y); o[2] = f2bf(a.z); o[3] = f2bf(a.w);
  o[4] = f2bf(b.x); o[5] = f2bf(b.y); o[6] = f2bf(b.z); o[7] = f2bf(b.w);
  ((u16x8*)out)[i] = o;
}

// W [1024][1024] fp32 row-major -> Wt [1024][1024] bf16, Wt[n][k] = W[k][n]
__global__ __launch_bounds__(256) void cvt_w_t(const float* __restrict__ W,
                                               u16* __restrict__ Wt) {
  __shared__ u16 t[64][65];
  const int tid = (int)threadIdx.x;
  const int r = tid >> 2;
  const int cs = (tid & 3) * 16;
  const int tr = (int)blockIdx.y * 64;
  const int tc = (int)blockIdx.x * 64;
#pragma unroll
  for (int i = 0; i < 16; i += 4) {
    const float4 v = *(const float4*)&W[(size_t)(tr + r) * 1024 + tc + cs + i];
    t[r][cs + i + 0] = f2bf(v.x);
    t[r][cs + i + 1] = f2bf(v.y);
    t[r][cs + i + 2] = f2bf(v.z);
    t[r][cs + i + 3] = f2bf(v.w);
  }
  __syncthreads();
  u16 tmp[16];
#pragma unroll
  for (int i = 0; i < 16; ++i) tmp[i] = t[cs + i][r];
  u16x8 o0, o1;
#pragma unroll
  for (int i = 0; i < 8; ++i) { o0[i] = tmp[i]; o1[i] = tmp[8 + i]; }
  *(u16x8*)&Wt[(size_t)(tc + r) * 1024 + tr + cs] = o0;
  *(u16x8*)&Wt[(size_t)(tc + r) * 1024 + tr + cs + 8] = o1;
}

// ---------------- GEMM: C[8192x1024] = A[8192x1024] @ Bt^T + bias ----------------
// OUT_MODE 0: bf16 row-major; 1: fp32 row-major (final out); 2: bf16 V-transposed [B,H,64,S]

template <int OUT_MODE>
__global__ __launch_bounds__(256) void gemm_bt(const u16* __restrict__ A,
                                               const u16* __restrict__ Bt,
                                               const float* __restrict__ bias,
                                               void* __restrict__ Cout) {
  constexpr int N = 1024, K = 1024;
  __shared__ __align__(16) u16 lds[2 * 128 * 64];
  const int tid = (int)threadIdx.x;
  const int w = tid >> 6, lane = tid & 63;
  const int wm = w >> 1, wn = w & 1;
  const int lr = lane & 15, lg = lane >> 4;
  const int mt = (int)blockIdx.y, nt = (int)blockIdx.x;

  const u16* Abase = A + (size_t)mt * 128 * K;
  const u16* Bbase = Bt + (size_t)nt * 128 * K;

  f32x4 acc[4][4] = {};

  for (int k0 = 0; k0 < K; k0 += 64) {
    stage_tile<128>(Abase + k0, K, lds, tid);
    stage_tile<128>(Bbase + k0, K, lds + 128 * 64, tid);
    __syncthreads();
#pragma unroll
    for (int ks = 0; ks < 2; ++ks) {
      bf16x8 af[4], bf[4];
#pragma unroll
      for (int i = 0; i < 4; ++i) {
        const int ar = wm * 64 + i * 16 + lr;
        af[i] = load_frag(lds, ar * 128 + ((ks * 64 + lg * 16) ^ ((ar & 7) << 4)));
        const int br = wn * 64 + i * 16 + lr;
        bf[i] = load_frag(lds + 128 * 64, br * 128 + ((ks * 64 + lg * 16) ^ ((br & 7) << 4)));
      }
#pragma unroll
      for (int mf = 0; mf < 4; ++mf)
#pragma unroll
        for (int nf = 0; nf < 4; ++nf) acc[mf][nf] = MFMA16(af[mf], bf[nf], acc[mf][nf]);
    }
    __syncthreads();
  }

#pragma unroll
  for (int mf = 0; mf < 4; ++mf) {
#pragma unroll
    for (int nf = 0; nf < 4; ++nf) {
      const int col = nt * 128 + wn * 64 + nf * 16 + lr;
      const float bv = bias[col];
#pragma unroll
      for (int r = 0; r < 4; ++r) {
        const int row = mt * 128 + wm * 64 + mf * 16 + lg * 4 + r;
        const float v = acc[mf][nf][r] + bv;
        if (OUT_MODE == 0) {
          ((u16*)Cout)[(size_t)row * N + col] = f2bf(v);
        } else if (OUT_MODE == 1) {
          ((float*)Cout)[(size_t)row * N + col] = v;
        } else {
          const int b = row >> 11, s = row & 2047;
          const int h = col >> 6, d = col & 63;
          ((u16*)Cout)[(size_t)((b * 16 + h) * 64 + d) * 2048 + s] = f2bf(v);
        }
      }
    }
  }
}

// ---------------- flash attention (causal), swapped-operand, LDS-free ----------------
// S^T = mfma(Kfrag, Qfrag): lane&31 = q-row; softmax fully in-register.
// O^T = mfma(Vfrag, Pfrag): lane&31 = q-row again -> m/l/rescale lane-local.

template <int MASKED>
__device__ __forceinline__ void attn_tile(const u16* __restrict__ kp,
                                          const u16* __restrict__ vp,
                                          const bf16x8 (&qf)[4], const int hi,
                                          const int tmask, f32x16& o0, f32x16& o1,
                                          float& m_run, float& l_run) {
  bf16x8 kf[2][4], vf[2][4];
#pragma unroll
  for (int sb = 0; sb < 2; ++sb)
#pragma unroll
    for (int dk = 0; dk < 4; ++dk)
      kf[sb][dk] = *(const bf16x8*)(kp + (size_t)sb * 32 * 1024 + dk * 16);
#pragma unroll
  for (int db = 0; db < 2; ++db)
#pragma unroll
    for (int ks = 0; ks < 4; ++ks)
      vf[db][ks] = *(const bf16x8*)(vp + (size_t)db * 32 * 2048 + ks * 16);

  // S^T: p0 = keys [0,32), p1 = keys [32,64); lane&31 = q, reg r -> k_local
  f32x16 p0 = {}, p1 = {};
#pragma unroll
  for (int dk = 0; dk < 4; ++dk) {
    p0 = MFMA32(kf[0][dk], qf[dk], p0);
    p1 = MFMA32(kf[1][dk], qf[dk], p1);
  }

  float mx = -3.0e38f;
#pragma unroll
  for (int r = 0; r < 16; ++r) {
    if (MASKED) {
      const int kl = (r & 3) + 8 * (r >> 2) + 4 * hi;
      if (kl > tmask) p0[r] = -1.0e30f;
      if (kl + 32 > tmask) p1[r] = -1.0e30f;
    }
    mx = fmaxf(mx, fmaxf(p0[r], p1[r]));
  }
  mx = fmaxf(mx, __shfl_xor(mx, 32));

  // defer-max (T13): THR = 8 in scaled units = 64 raw
  if (__any(mx > m_run + 64.0f)) {
    const float mnew = fmaxf(m_run, mx);
    const float alpha = __expf((m_run - mnew) * 0.125f);
    m_run = mnew;
    l_run *= alpha;
#pragma unroll
    for (int r = 0; r < 16; ++r) { o0[r] *= alpha; o1[r] *= alpha; }
  }

  float rs = 0.0f;
#pragma unroll
  for (int r = 0; r < 16; ++r) {
    p0[r] = __expf((p0[r] - m_run) * 0.125f);
    p1[r] = __expf((p1[r] - m_run) * 0.125f);
    rs += p0[r] + p1[r];
  }
  rs += __shfl_xor(rs, 32);
  l_run += rs;

  // P^T B-fragments: 16 packed words + cross-half exchange (permlane-equivalent)
  unsigned c[16];
#pragma unroll
  for (int r2 = 0; r2 < 8; ++r2) {
    c[r2] = pack_bf2(p0[2 * r2], p0[2 * r2 + 1]);
    c[8 + r2] = pack_bf2(p1[2 * r2], p1[2 * r2 + 1]);
  }
  bf16x8 pf[4];
#pragma unroll
  for (int ks = 0; ks < 4; ++ks) {
    const int base = (ks >> 1) * 8 + (ks & 1) * 4;
    const unsigned x = __shfl_xor(hi ? c[base + 0] : c[base + 2], 32);
    const unsigned y = __shfl_xor(hi ? c[base + 1] : c[base + 3], 32);
    u32x4 wv;
    wv[0] = hi ? x : c[base + 0];
    wv[1] = hi ? y : c[base + 1];
    wv[2] = hi ? c[base + 2] : x;
    wv[3] = hi ? c[base + 3] : y;
    pf[ks] = __builtin_bit_cast(bf16x8, wv);
  }

  // O^T += V^T . P^T
#pragma unroll
  for (int ks = 0; ks < 4; ++ks) {
    o0 = MFMA32(vf[0][ks], pf[ks], o0);
    o1 = MFMA32(vf[1][ks], pf[ks], o1);
  }
}

__global__ __launch_bounds__(256) void attn_fwd(const u16* __restrict__ Qb,
                                                const u16* __restrict__ Kb,
                                                const u16* __restrict__ Vt,
                                                u16* __restrict__ Ab) {
  const int tid = (int)threadIdx.x;
  const int w = tid >> 6, lane = tid & 63;
  const int ln = lane & 31, hi = lane >> 5;

  // XCD swizzle: co-locate each bh's 16 q-blocks on one XCD; heavy q-tiles first
  const int id = (int)blockIdx.x;
  const int xcd = id & 7, slot = id >> 3;
  const int bh = (xcd << 3) | (slot & 7);
  const int qt = 15 - (slot >> 3);
  const int b = bh >> 4, h = bh & 15;
  const int wq = qt * 128 + w * 32;
  const int qrow = wq + ln;

  const u16* qp = Qb + (size_t)(b * 2048 + qrow) * 1024 + h * 64 + hi * 8;
  bf16x8 qf[4];
#pragma unroll
  for (int dk = 0; dk < 4; ++dk) qf[dk] = *(const bf16x8*)(qp + dk * 16);

  const u16* kp = Kb + (size_t)(b * 2048 + ln) * 1024 + h * 64 + hi * 8;
  const u16* vp = Vt + (size_t)(bh * 64 + ln) * 2048 + hi * 8;

  f32x16 o0 = {}, o1 = {};
  float m_run = -3.0e38f, l_run = 0.0f;

  const int nfull = (wq + 1) >> 6;
  for (int j = 0; j < nfull; ++j)
    attn_tile<0>(kp + (size_t)j * 64 * 1024, vp + j * 64, qf, hi, 0, o0, o1, m_run, l_run);
  attn_tile<1>(kp + (size_t)nfull * 64 * 1024, vp + nfull * 64, qf, hi,
               qrow - nfull * 64, o0, o1, m_run, l_run);

  const float inv = 1.0f / l_run;
  u16* op = Ab + (size_t)(b * 2048 + qrow) * 1024 + h * 64;
#pragma unroll
  for (int rr = 0; rr < 4; ++rr) {
    u16x4 s0v, s1v;
#pragma unroll
    for (int cc = 0; cc < 4; ++cc) {
      s0v[cc] = f2bf(o0[rr * 4 + cc] * inv);
      s1v[cc] = f2bf(o1[rr * 4 + cc] * inv);
    }
    *(u16x4*)(op + rr * 8 + hi * 4) = s0v;       // d = 8*rr + 4*hi + 0..3
    *(u16x4*)(op + 32 + rr * 8 + hi * 4) = s1v;  // d = 32 + ...
  }
}

// ---------------- launch ----------------

extern "C" void kernel_launch(void* const* d_in, const int* in_sizes, int n_in, void* d_out,
                              int out_size, void* d_ws, size_t ws_size, hipStream_t stream) {
  const float* X = (const float*)d_in[0];
  const float* Wq = (const float*)d_in[1];
  const float* bq = (const float*)d_in[2];
  const float* Wk = (const float*)d_in[3];
  const float* bk = (const float*)d_in[4];
  const float* Wv = (const float*)d_in[5];
  const float* bv = (const float*)d_in[6];
  const float* Wo = (const float*)d_in[7];
  const float* bo = (const float*)d_in[8];
  float* out = (float*)d_out;

  u16* ws = (u16*)d_ws;
  u16* Xb = ws;                    // 8192x1024 bf16 X
  u16* Wqt = Xb + 8388608;         // 1024x1024 bf16 Wq^T
  u16* Wkt = Wqt + 1048576;
  u16* Wvt = Wkt + 1048576;
  u16* Wot = Wvt + 1048576;
  u16* Qb = Wot + 1048576;         // 8192x1024 bf16 Q
  u16* Kb = Qb + 8388608;          // 8192x1024 bf16 K
  u16* Vt = Kb + 8388608;          // [B,H,64,2048] bf16 V^T
  u16* Ab = Vt + 8388608;          // 8192x1024 bf16 attn out

  cvt_x<<<4096, 256, 0, stream>>>(X, Xb);
  dim3 wtg(16, 16);
  cvt_w_t<<<wtg, 256, 0, stream>>>(Wq, Wqt);
  cvt_w_t<<<wtg, 256, 0, stream>>>(Wk, Wkt);
  cvt_w_t<<<wtg, 256, 0, stream>>>(Wv, Wvt);
  cvt_w_t<<<wtg, 256, 0, stream>>>(Wo, Wot);

  dim3 gg(8, 64);
  gemm_bt<0><<<gg, 256, 0, stream>>>(Xb, Wqt, bq, Qb);
  gemm_bt<0><<<gg, 256, 0, stream>>>(Xb, Wkt, bk, Kb);
  gemm_bt<2><<<gg, 256, 0, stream>>>(Xb, Wvt, bv, Vt);

  attn_fwd<<<1024, 256, 0, stream>>>(Qb, Kb, Vt, Ab);

  gemm_bt<1><<<gg, 256, 0, stream>>>(Ab, Wot, bo, out);
}

// Round 4
// 202.487 us; speedup vs baseline: 1.3600x; 1.2438x over previous
//
#include <hip/hip_runtime.h>
#include <stdint.h>

typedef unsigned short u16;
typedef __bf16 bf16x8 __attribute__((ext_vector_type(8)));
typedef float f32x4 __attribute__((ext_vector_type(4)));
typedef float f32x16 __attribute__((ext_vector_type(16)));
typedef unsigned int u32x4 __attribute__((ext_vector_type(4)));
typedef u16 u16x8 __attribute__((ext_vector_type(8)));
typedef u16 u16x4 __attribute__((ext_vector_type(4)));

#define MFMA16(a, b, c) __builtin_amdgcn_mfma_f32_16x16x32_bf16((a), (b), (c), 0, 0, 0)
#define MFMA32(a, b, c) __builtin_amdgcn_mfma_f32_32x32x16_bf16((a), (b), (c), 0, 0, 0)

__device__ __forceinline__ u16 f2bf(float f) {
  unsigned u = __float_as_uint(f);
  u += 0x7fff + ((u >> 16) & 1);  // RNE
  return (u16)(u >> 16);
}

__device__ __forceinline__ unsigned pack_bf2(float lo, float hi) {
  return (unsigned)f2bf(lo) | ((unsigned)f2bf(hi) << 16);
}

__device__ __forceinline__ bf16x8 load_frag(const u16* lds_base, int byteoff) {
  u32x4 v = *(const u32x4*)((const char*)lds_base + byteoff);
  return __builtin_bit_cast(bf16x8, v);
}

#define GLOAD_LDS16(gp, lp)                                                        \
  __builtin_amdgcn_global_load_lds((const __attribute__((address_space(1))) void*)(gp), \
                                   (__attribute__((address_space(3))) void*)(lp), 16, 0, 0)

// Stage ROWS x 64-bf16 tile (128B rows) from global (row stride ld elems) into
// swizzled LDS. Physical 16B-slot `seg` holds logical slot `seg ^ (row&7)`.
template <int ROWS>
__device__ __forceinline__ void stage_tile(const u16* __restrict__ src, int ld, u16* lds,
                                           int tid) {
  constexpr int SLOTS = ROWS * 8;
#pragma unroll
  for (int it = 0; it < SLOTS / 256; ++it) {
    const int s = it * 256 + tid;
    const int row = s >> 3;
    const int seg = (s & 7) ^ (row & 7);
    const u16* g = src + row * ld + seg * 8;
    u16* l = lds + (it * 256 + (tid & ~63)) * 8;  // wave-uniform base; HW adds lane*16
    GLOAD_LDS16(g, l);
  }
}

// ---------------- converts ----------------

__global__ __launch_bounds__(256) void cvt_x(const float* __restrict__ in,
                                             u16* __restrict__ out) {
  const int i = (int)blockIdx.x * 256 + (int)threadIdx.x;
  const float4 a = ((const float4*)in)[2 * i];
  const float4 b = ((const float4*)in)[2 * i + 1];
  u16x8 o;
  o[0] = f2bf(a.x); o[1] = f2bf(a.y); o[2] = f2bf(a.z); o[3] = f2bf(a.w);
  o[4] = f2bf(b.x); o[5] = f2bf(b.y); o[6] = f2bf(b.z); o[7] = f2bf(b.w);
  ((u16x8*)out)[i] = o;
}

// W [1024][1024] fp32 row-major -> Wt [1024][1024] bf16, Wt[n][k] = W[k][n]
__global__ __launch_bounds__(256) void cvt_w_t(const float* __restrict__ W,
                                               u16* __restrict__ Wt) {
  __shared__ u16 t[64][65];
  const int tid = (int)threadIdx.x;
  const int r = tid >> 2;
  const int cs = (tid & 3) * 16;
  const int tr = (int)blockIdx.y * 64;
  const int tc = (int)blockIdx.x * 64;
#pragma unroll
  for (int i = 0; i < 16; i += 4) {
    const float4 v = *(const float4*)&W[(size_t)(tr + r) * 1024 + tc + cs + i];
    t[r][cs + i + 0] = f2bf(v.x);
    t[r][cs + i + 1] = f2bf(v.y);
    t[r][cs + i + 2] = f2bf(v.z);
    t[r][cs + i + 3] = f2bf(v.w);
  }
  __syncthreads();
  u16 tmp[16];
#pragma unroll
  for (int i = 0; i < 16; ++i) tmp[i] = t[cs + i][r];
  u16x8 o0, o1;
#pragma unroll
  for (int i = 0; i < 8; ++i) { o0[i] = tmp[i]; o1[i] = tmp[8 + i]; }
  *(u16x8*)&Wt[(size_t)(tc + r) * 1024 + tr + cs] = o0;
  *(u16x8*)&Wt[(size_t)(tc + r) * 1024 + tr + cs + 8] = o1;
}

// ---------------- GEMM: C[8192x1024] = A[8192x1024] @ Bt^T + bias ----------------
// OUT_MODE 0: bf16 row-major; 1: fp32 row-major (final out);
// OUT_MODE 2: V in PV A-fragment layout  Vf[bh][tile64][db][ks][lane][8]
// OUT_MODE 3: K in QK A-fragment layout  Kf[bh][kb32][dk][lane][8]

template <int OUT_MODE>
__global__ __launch_bounds__(256) void gemm_bt(const u16* __restrict__ A,
                                               const u16* __restrict__ Bt,
                                               const float* __restrict__ bias,
                                               void* __restrict__ Cout) {
  constexpr int N = 1024, K = 1024;
  __shared__ __align__(16) u16 lds[2 * 128 * 64];
  const int tid = (int)threadIdx.x;
  const int w = tid >> 6, lane = tid & 63;
  const int wm = w >> 1, wn = w & 1;
  const int lr = lane & 15, lg = lane >> 4;
  const int mt = (int)blockIdx.y, nt = (int)blockIdx.x;

  const u16* Abase = A + (size_t)mt * 128 * K;
  const u16* Bbase = Bt + (size_t)nt * 128 * K;

  f32x4 acc[4][4] = {};

  for (int k0 = 0; k0 < K; k0 += 64) {
    stage_tile<128>(Abase + k0, K, lds, tid);
    stage_tile<128>(Bbase + k0, K, lds + 128 * 64, tid);
    __syncthreads();
#pragma unroll
    for (int ks = 0; ks < 2; ++ks) {
      bf16x8 af[4], bf[4];
#pragma unroll
      for (int i = 0; i < 4; ++i) {
        const int ar = wm * 64 + i * 16 + lr;
        af[i] = load_frag(lds, ar * 128 + ((ks * 64 + lg * 16) ^ ((ar & 7) << 4)));
        const int br = wn * 64 + i * 16 + lr;
        bf[i] = load_frag(lds + 128 * 64, br * 128 + ((ks * 64 + lg * 16) ^ ((br & 7) << 4)));
      }
#pragma unroll
      for (int mf = 0; mf < 4; ++mf)
#pragma unroll
        for (int nf = 0; nf < 4; ++nf) acc[mf][nf] = MFMA16(af[mf], bf[nf], acc[mf][nf]);
    }
    __syncthreads();
  }

#pragma unroll
  for (int mf = 0; mf < 4; ++mf) {
#pragma unroll
    for (int nf = 0; nf < 4; ++nf) {
      const int col = nt * 128 + wn * 64 + nf * 16 + lr;
      const float bv = bias[col];
#pragma unroll
      for (int r = 0; r < 4; ++r) {
        const int row = mt * 128 + wm * 64 + mf * 16 + lg * 4 + r;
        const float v = acc[mf][nf][r] + bv;
        if (OUT_MODE == 0) {
          ((u16*)Cout)[(size_t)row * N + col] = f2bf(v);
        } else if (OUT_MODE == 1) {
          ((float*)Cout)[(size_t)row * N + col] = v;
        } else if (OUT_MODE == 2) {
          // V fragment layout: key = row (within bh), d = col&63
          const int b = row >> 11, s = row & 2047;
          const int h = col >> 6, d = col & 63;
          const size_t addr = ((size_t)((b * 16 + h) * 32 + (s >> 6))) * 4096 +
                              (size_t)(d >> 5) * 2048 + (size_t)((s & 63) >> 4) * 512 +
                              (size_t)((d & 31) | (((s >> 3) & 1) << 5)) * 8 + (s & 7);
          ((u16*)Cout)[addr] = f2bf(v);
        } else {
          // K fragment layout
          const int b = row >> 11, s = row & 2047;
          const int h = col >> 6, d = col & 63;
          const size_t addr = ((size_t)((b * 16 + h) * 64 + (s >> 5))) * 2048 +
                              (size_t)(d >> 4) * 512 +
                              (size_t)((s & 31) | (((d >> 3) & 1) << 5)) * 8 + (d & 7);
          ((u16*)Cout)[addr] = f2bf(v);
        }
      }
    }
  }
}

// ---------------- flash attention (causal), swapped-operand, LDS-free ----------------
// S^T = mfma(Kfrag, Qfrag): lane&31 = q-row; softmax fully in-register.
// O^T = mfma(Vfrag, Pfrag): lane&31 = q-row again -> m/l/rescale lane-local.
// K/V read from fragment-order layouts: every load is a coalesced 1KB wave txn.

template <int MASKED>
__device__ __forceinline__ void attn_tile(const u16* __restrict__ kp,
                                          const u16* __restrict__ vp,
                                          const bf16x8 (&qf)[4], const int hi,
                                          const int tmask, f32x16& o0, f32x16& o1,
                                          float& m_run, float& l_run) {
  bf16x8 kf[2][4], vf[2][4];
#pragma unroll
  for (int sb = 0; sb < 2; ++sb)
#pragma unroll
    for (int dk = 0; dk < 4; ++dk)
      kf[sb][dk] = *(const bf16x8*)(kp + sb * 2048 + dk * 512);
#pragma unroll
  for (int db = 0; db < 2; ++db)
#pragma unroll
    for (int ks = 0; ks < 4; ++ks)
      vf[db][ks] = *(const bf16x8*)(vp + db * 2048 + ks * 512);

  // S^T: p0 = keys [0,32), p1 = keys [32,64); lane&31 = q, reg r -> k_local
  f32x16 p0 = {}, p1 = {};
#pragma unroll
  for (int dk = 0; dk < 4; ++dk) {
    p0 = MFMA32(kf[0][dk], qf[dk], p0);
    p1 = MFMA32(kf[1][dk], qf[dk], p1);
  }

  float mx = -3.0e38f;
#pragma unroll
  for (int r = 0; r < 16; ++r) {
    if (MASKED) {
      const int kl = (r & 3) + 8 * (r >> 2) + 4 * hi;
      if (kl > tmask) p0[r] = -1.0e30f;
      if (kl + 32 > tmask) p1[r] = -1.0e30f;
    }
    mx = fmaxf(mx, fmaxf(p0[r], p1[r]));
  }
  mx = fmaxf(mx, __shfl_xor(mx, 32));

  // defer-max (T13): THR = 8 in scaled units = 64 raw
  if (__any(mx > m_run + 64.0f)) {
    const float mnew = fmaxf(m_run, mx);
    const float alpha = __expf((m_run - mnew) * 0.125f);
    m_run = mnew;
    l_run *= alpha;
#pragma unroll
    for (int r = 0; r < 16; ++r) { o0[r] *= alpha; o1[r] *= alpha; }
  }

  float rs = 0.0f;
#pragma unroll
  for (int r = 0; r < 16; ++r) {
    p0[r] = __expf((p0[r] - m_run) * 0.125f);
    p1[r] = __expf((p1[r] - m_run) * 0.125f);
    rs += p0[r] + p1[r];
  }
  rs += __shfl_xor(rs, 32);
  l_run += rs;

  // P^T B-fragments: 16 packed words + cross-half exchange (permlane-equivalent)
  unsigned c[16];
#pragma unroll
  for (int r2 = 0; r2 < 8; ++r2) {
    c[r2] = pack_bf2(p0[2 * r2], p0[2 * r2 + 1]);
    c[8 + r2] = pack_bf2(p1[2 * r2], p1[2 * r2 + 1]);
  }
  bf16x8 pf[4];
#pragma unroll
  for (int ks = 0; ks < 4; ++ks) {
    const int base = (ks >> 1) * 8 + (ks & 1) * 4;
    const unsigned x = __shfl_xor(hi ? c[base + 0] : c[base + 2], 32);
    const unsigned y = __shfl_xor(hi ? c[base + 1] : c[base + 3], 32);
    u32x4 wv;
    wv[0] = hi ? x : c[base + 0];
    wv[1] = hi ? y : c[base + 1];
    wv[2] = hi ? c[base + 2] : x;
    wv[3] = hi ? c[base + 3] : y;
    pf[ks] = __builtin_bit_cast(bf16x8, wv);
  }

  // O^T += V^T . P^T
#pragma unroll
  for (int ks = 0; ks < 4; ++ks) {
    o0 = MFMA32(vf[0][ks], pf[ks], o0);
    o1 = MFMA32(vf[1][ks], pf[ks], o1);
  }
}

__global__ __launch_bounds__(256) void attn_fwd(const u16* __restrict__ Qb,
                                                const u16* __restrict__ Kf,
                                                const u16* __restrict__ Vf,
                                                u16* __restrict__ Ab) {
  const int tid = (int)threadIdx.x;
  const int w = tid >> 6, lane = tid & 63;
  const int ln = lane & 31, hi = lane >> 5;

  // XCD swizzle: co-locate each bh's 16 q-blocks on one XCD; heavy q-tiles first
  const int id = (int)blockIdx.x;
  const int xcd = id & 7, slot = id >> 3;
  const int bh = (xcd << 3) | (slot & 7);
  const int qt = 15 - (slot >> 3);
  const int b = bh >> 4, h = bh & 15;
  const int wq = qt * 128 + w * 32;
  const int qrow = wq + ln;

  const u16* qp = Qb + (size_t)(b * 2048 + qrow) * 1024 + h * 64 + hi * 8;
  bf16x8 qf[4];
#pragma unroll
  for (int dk = 0; dk < 4; ++dk) qf[dk] = *(const bf16x8*)(qp + dk * 16);

  // fragment-layout bases (per-lane contiguous 16B)
  const u16* kp = Kf + (size_t)bh * 131072 + lane * 8;
  const u16* vp = Vf + (size_t)bh * 131072 + lane * 8;

  f32x16 o0 = {}, o1 = {};
  float m_run = -3.0e38f, l_run = 0.0f;

  const int nfull = (wq + 1) >> 6;
  for (int j = 0; j < nfull; ++j)
    attn_tile<0>(kp + (size_t)j * 4096, vp + (size_t)j * 4096, qf, hi, 0, o0, o1, m_run, l_run);
  attn_tile<1>(kp + (size_t)nfull * 4096, vp + (size_t)nfull * 4096, qf, hi,
               qrow - nfull * 64, o0, o1, m_run, l_run);

  const float inv = 1.0f / l_run;
  u16* op = Ab + (size_t)(b * 2048 + qrow) * 1024 + h * 64;
#pragma unroll
  for (int rr = 0; rr < 4; ++rr) {
    u16x4 s0v, s1v;
#pragma unroll
    for (int cc = 0; cc < 4; ++cc) {
      s0v[cc] = f2bf(o0[rr * 4 + cc] * inv);
      s1v[cc] = f2bf(o1[rr * 4 + cc] * inv);
    }
    *(u16x4*)(op + rr * 8 + hi * 4) = s0v;       // d = 8*rr + 4*hi + 0..3
    *(u16x4*)(op + 32 + rr * 8 + hi * 4) = s1v;  // d = 32 + ...
  }
}

// ---------------- launch ----------------

extern "C" void kernel_launch(void* const* d_in, const int* in_sizes, int n_in, void* d_out,
                              int out_size, void* d_ws, size_t ws_size, hipStream_t stream) {
  const float* X = (const float*)d_in[0];
  const float* Wq = (const float*)d_in[1];
  const float* bq = (const float*)d_in[2];
  const float* Wk = (const float*)d_in[3];
  const float* bk = (const float*)d_in[4];
  const float* Wv = (const float*)d_in[5];
  const float* bv = (const float*)d_in[6];
  const float* Wo = (const float*)d_in[7];
  const float* bo = (const float*)d_in[8];
  float* out = (float*)d_out;

  u16* ws = (u16*)d_ws;
  u16* Xb = ws;                    // 8192x1024 bf16 X
  u16* Wqt = Xb + 8388608;         // 1024x1024 bf16 Wq^T
  u16* Wkt = Wqt + 1048576;
  u16* Wvt = Wkt + 1048576;
  u16* Wot = Wvt + 1048576;
  u16* Qb = Wot + 1048576;         // 8192x1024 bf16 Q
  u16* Kf = Qb + 8388608;          // K fragment layout [bh][kb32][dk][lane][8]
  u16* Vf = Kf + 8388608;          // V fragment layout [bh][tile64][db][ks][lane][8]
  u16* Ab = Vf + 8388608;          // 8192x1024 bf16 attn out

  cvt_x<<<4096, 256, 0, stream>>>(X, Xb);
  dim3 wtg(16, 16);
  cvt_w_t<<<wtg, 256, 0, stream>>>(Wq, Wqt);
  cvt_w_t<<<wtg, 256, 0, stream>>>(Wk, Wkt);
  cvt_w_t<<<wtg, 256, 0, stream>>>(Wv, Wvt);
  cvt_w_t<<<wtg, 256, 0, stream>>>(Wo, Wot);

  dim3 gg(8, 64);
  gemm_bt<0><<<gg, 256, 0, stream>>>(Xb, Wqt, bq, Qb);
  gemm_bt<3><<<gg, 256, 0, stream>>>(Xb, Wkt, bk, Kf);
  gemm_bt<2><<<gg, 256, 0, stream>>>(Xb, Wvt, bv, Vf);

  attn_fwd<<<1024, 256, 0, stream>>>(Qb, Kf, Vf, Ab);

  gemm_bt<1><<<gg, 256, 0, stream>>>(Ab, Wot, bo, out);
}